// Round 4
// baseline (359.929 us; speedup 1.0000x reference)
//
#include <hip/hip_runtime.h>
#include <hip/hip_bf16.h>
#include <hip/hip_cooperative_groups.h>

namespace cg = cooperative_groups;

typedef __attribute__((ext_vector_type(8))) short bf16x8;
typedef __attribute__((ext_vector_type(4))) float f32x4;

#define LOG2E 1.44269504088896340736f

// ---- workspace layout ----
// bf16 element offsets
#define XQ_OFF 0
#define XK_OFF 524288
#define XV_OFF 1048576
#define WQ_OFF 1572864
#define WK_OFF 1835008
#define WV_OFF 2097152
#define WO_OFF 2359296
#define QB_OFF 2621440
#define KB_OFF 3145728
#define VT_OFF 3670016
#define AO_OFF 4194304
// byte offsets (fp32 tables / seg indices)
#define T_B   9437184
#define A_B   (T_B + 4096)
#define C_B   (A_B + 20480)
#define SEG_B (C_B + 20480)

#define SMEM_BYTES 37120

struct MegaArgs {
  const float *xq, *xk, *xv, *eg;
  const float *wq, *wk, *wv, *wo;
  const float *bq, *bk, *bv, *bo;
  const float *w1, *b1, *we2, *be2;
  float* out;
  unsigned short* wsb;
  float *wsT, *wsA, *wsC;
  unsigned short* segp;
};

__device__ __forceinline__ unsigned short f2bf(float f) {
  union { __hip_bfloat16 h; unsigned short u; } c;
  c.h = __float2bfloat16(f);
  return c.u;
}

// ---------------- phase 0a: edge-MLP -> exact PWL tables (1 block, 256 threads) ----------------
// f_h(e) = sum_k We2[k,h]*relu(e*w1[k]+b1[k]) + be2[h] is PWL with breakpoints t_k=-b1/w1.
__device__ void prep_block(const MegaArgs& a, char* smem) {
  float* sT   = (float*)smem;                      // 2048
  int*   sIdx = (int*)(smem + 2048);               // 2048
  float (*sDA)[8] = (float (*)[8])(smem + 4096);   // 16384
  float (*sDC)[8] = (float (*)[8])(smem + 20480);  // 16384
  float* sA0 = (float*)(smem + 36864);             // 32
  float* sC0 = (float*)(smem + 36896);             // 32
  int tid = threadIdx.x;
  for (int p = tid; p < 512; p += 256) {
    float w = a.w1[p], bb = a.b1[p];
    sT[p] = (w != 0.f) ? (-bb / w) : -3.4e38f;  // w==0: never a real crossing
    sIdx[p] = p;
    // seg-0 contributions (active set = {k : w1[k] < 0}; w==0 contributes const relu(b))
#pragma unroll
    for (int h = 0; h < 8; ++h) {
      float w2 = a.we2[p * 8 + h];
      float ra = 0.f, rc = 0.f;
      if (w < 0.f)       { ra = w2 * w; rc = w2 * bb; }
      else if (w == 0.f) { rc = w2 * fmaxf(bb, 0.f); }
      sDA[p][h] = ra; sDC[p][h] = rc;
    }
  }
  __syncthreads();
  // bitonic sort ascending: 256 compare-exchange pairs per substage
  for (int size = 2; size <= 512; size <<= 1) {
    for (int stride = size >> 1; stride > 0; stride >>= 1) {
      int p = tid;
      int i = ((p / stride) * (stride << 1)) + (p % stride);
      int j = i + stride;
      bool up = ((i & size) == 0);
      float ti = sT[i], tj = sT[j];
      if (up ? (ti > tj) : (ti < tj)) {
        sT[i] = tj; sT[j] = ti;
        int t = sIdx[i]; sIdx[i] = sIdx[j]; sIdx[j] = t;
      }
      __syncthreads();
    }
  }
  // tree-reduce seg0 contributions (order-independent of the sort)
#pragma unroll
  for (int h = 0; h < 8; ++h) { sDA[tid][h] += sDA[tid + 256][h]; sDC[tid][h] += sDC[tid + 256][h]; }
  __syncthreads();
  for (int st = 128; st > 0; st >>= 1) {
    if (tid < st) {
#pragma unroll
      for (int h = 0; h < 8; ++h) { sDA[tid][h] += sDA[tid + st][h]; sDC[tid][h] += sDC[tid + st][h]; }
    }
    __syncthreads();
  }
  if (tid < 8) { sA0[tid] = sDA[0][tid]; sC0[tid] = sDC[0][tid] + a.be2[tid]; }
  __syncthreads();
  // per-sorted-position deltas
  for (int p = tid; p < 512; p += 256) {
    int k = sIdx[p];
    float wk = a.w1[k], bk2 = a.b1[k];
#pragma unroll
    for (int h = 0; h < 8; ++h) {
      float w2 = a.we2[k * 8 + h];
      float da = 0.f, dc = 0.f;
      if (wk > 0.f)      { da =  w2 * wk; dc =  w2 * bk2; }
      else if (wk < 0.f) { da = -w2 * wk; dc = -w2 * bk2; }
      sDA[p][h] = da; sDC[p][h] = dc;
    }
  }
  __syncthreads();
  // inclusive Hillis-Steele scan over 512 sorted positions, 2 per thread
  for (int off = 1; off < 512; off <<= 1) {
    float ra[2][8], rc[2][8];
#pragma unroll
    for (int e = 0; e < 2; ++e) {
      int p = tid + e * 256;
      if (p >= off) {
#pragma unroll
        for (int h = 0; h < 8; ++h) { ra[e][h] = sDA[p - off][h]; rc[e][h] = sDC[p - off][h]; }
      }
    }
    __syncthreads();
#pragma unroll
    for (int e = 0; e < 2; ++e) {
      int p = tid + e * 256;
      if (p >= off) {
#pragma unroll
        for (int h = 0; h < 8; ++h) { sDA[p][h] += ra[e][h]; sDC[p][h] += rc[e][h]; }
      }
    }
    __syncthreads();
  }
  a.wsT[tid] = sT[tid]; a.wsT[tid + 256] = sT[tid + 256];
  if (tid < 8) { a.wsA[tid] = sA0[tid]; a.wsC[tid] = sC0[tid]; }
  for (int p = tid; p < 512; p += 256) {
#pragma unroll
    for (int h = 0; h < 8; ++h) {
      a.wsA[(p + 1) * 8 + h] = sA0[h] + sDA[p][h];
      a.wsC[(p + 1) * 8 + h] = sC0[h] + sDC[p][h];
    }
  }
}

// ---------------- phase 0b: two 64x64 weight-transpose tiles (LDS-staged, coalesced) ------------
__device__ void transpose2(const MegaArgs& a, int tblk, char* smem) {
  unsigned short (*sWt)[72] = (unsigned short (*)[72])smem;
  int tid = threadIdx.x;
  for (int it = 0; it < 2; ++it) {
    int t = tblk * 2 + it;
    int mat = t >> 6, tile = t & 63;
    int k0 = (tile >> 3) * 64, n0 = (tile & 7) * 64;
    const float* src = (mat == 0) ? a.wq : (mat == 1) ? a.wk : (mat == 2) ? a.wv : a.wo;
    int row = tid >> 2, cq = tid & 3;
    const float4* sp = (const float4*)(src + (size_t)(k0 + row) * 512 + n0 + cq * 16);
    if (it) __syncthreads();
#pragma unroll
    for (int j2 = 0; j2 < 4; ++j2) {
      float4 v = sp[j2];
      int nl = cq * 16 + j2 * 4;
      sWt[nl + 0][row] = f2bf(v.x);
      sWt[nl + 1][row] = f2bf(v.y);
      sWt[nl + 2][row] = f2bf(v.z);
      sWt[nl + 3][row] = f2bf(v.w);
    }
    __syncthreads();
    int n = tid >> 2, kq = tid & 3;
    unsigned short* dst = a.wsb + WQ_OFF + mat * 262144 + (size_t)(n0 + n) * 512 + k0 + kq * 16;
    *(uint4*)dst       = *(const uint4*)&sWt[n][kq * 16];
    *(uint4*)(dst + 8) = *(const uint4*)&sWt[n][kq * 16 + 8];
  }
}

// ---------------- phase 0c: x fp32->bf16 convert, grid-strided units of 256 float4 --------------
__device__ void convert_units(const MegaArgs& a, int blk) {
  int tid = threadIdx.x;
  for (int u = blk - 129; u < 1536; u += 383) {
    int i = u * 256 + tid;
    int region = i >> 17, off = i & 131071;
    const float* src = (region == 0) ? a.xq : (region == 1) ? a.xk : a.xv;
    float4 v = ((const float4*)src)[off];
    ushort4 o;
    o.x = f2bf(v.x); o.y = f2bf(v.y); o.z = f2bf(v.z); o.w = f2bf(v.w);
    ((ushort4*)a.wsb)[i] = o;
  }
}

// ---------------- phase 1b: per-edge segment index (binary search over sorted breakpoints) ------
__device__ void seg_block(const MegaArgs& a, int sblk, char* smem) {
  float* sT = (float*)smem;
  int tid = threadIdx.x;
  sT[tid] = a.wsT[tid]; sT[tid + 256] = a.wsT[tid + 256];
  __syncthreads();
  int base = sblk * 4096;
  for (int j2 = 0; j2 < 16; ++j2) {
    int i = base + j2 * 256 + tid;
    float ev = a.eg[i];
    int lo = 0, hi = 512;
    while (lo < hi) {  // count of T[s] < ev
      int mid = (lo + hi) >> 1;
      if (sT[mid] < ev) lo = mid + 1; else hi = mid;
    }
    a.segp[i] = (unsigned short)lo;
  }
}

// ---------------- bf16 MFMA GEMM tile: Y = X @ Wt^T + bias (64x64, K=512) -----------------------
__device__ void gemm_tile(const unsigned short* __restrict__ A, const unsigned short* __restrict__ Wt,
                          const float* __restrict__ bias, void* out, int mode,
                          int m0, int n0, char* smem) {
  const int K = 512;
  unsigned short (*sA)[72]  = (unsigned short (*)[72])smem;
  unsigned short (*sBt)[72] = (unsigned short (*)[72])(smem + 9216);
  int tid = threadIdx.x, wave = tid >> 6, lane = tid & 63;
  int quad = lane >> 4, l16 = lane & 15;
  f32x4 acc[4] = {{0.f,0.f,0.f,0.f},{0.f,0.f,0.f,0.f},{0.f,0.f,0.f,0.f},{0.f,0.f,0.f,0.f}};
  int lr = tid >> 2, ls = tid & 3;
  for (int kb = 0; kb < K; kb += 64) {
    __syncthreads();
    *(uint4*)&sA[lr][ls * 16]      = *(const uint4*)(A  + (size_t)(m0 + lr) * K + kb + ls * 16);
    *(uint4*)&sA[lr][ls * 16 + 8]  = *(const uint4*)(A  + (size_t)(m0 + lr) * K + kb + ls * 16 + 8);
    *(uint4*)&sBt[lr][ls * 16]     = *(const uint4*)(Wt + (size_t)(n0 + lr) * K + kb + ls * 16);
    *(uint4*)&sBt[lr][ls * 16 + 8] = *(const uint4*)(Wt + (size_t)(n0 + lr) * K + kb + ls * 16 + 8);
    __syncthreads();
    for (int ks = 0; ks < 2; ++ks) {
      bf16x8 af = *(const bf16x8*)&sA[wave * 16 + l16][ks * 32 + quad * 8];
#pragma unroll
      for (int nt = 0; nt < 4; ++nt) {
        bf16x8 bf = *(const bf16x8*)&sBt[nt * 16 + l16][ks * 32 + quad * 8];
        acc[nt] = __builtin_amdgcn_mfma_f32_16x16x32_bf16(af, bf, acc[nt], 0, 0, 0);
      }
    }
  }
  __syncthreads();  // allow caller to reuse smem afterwards
  int mbase = m0 + wave * 16 + quad * 4;  // C row = quad*4+reg (m89-verified)
#pragma unroll
  for (int nt = 0; nt < 4; ++nt) {
    int n = n0 + nt * 16 + l16;
    float bv = bias[n];
#pragma unroll
    for (int r = 0; r < 4; ++r) {
      float v = acc[nt][r] + bv;
      int m = mbase + r;
      if (mode == 0) {
        int b = m >> 9, l = m & 511, hh = n >> 6, d = n & 63;
        ((unsigned short*)out)[(((size_t)(b * 8 + hh) * 512) + l) * 64 + d] = f2bf(v);
      } else if (mode == 1) {
        ((float*)out)[(size_t)m * 512 + n] = v;
      } else {
        int b = m >> 9, l = m & 511, hh = n >> 6, d = n & 63;
        ((unsigned short*)out)[(((size_t)(b * 8 + hh) * 64) + d) * 512 + l] = f2bf(v);
      }
    }
  }
}

// ---------------- phase 2: fused edge-bias attention (16 q-rows/block, waves split keys) --------
__device__ void attn_block(const MegaArgs& a, int qt, int h, int b, char* smem) {
  float* sAh = (float*)smem;                                            // 2052
  float* sCh = (float*)(smem + 2052);                                   // 2052
  unsigned short (*sP)[16][40] = (unsigned short (*)[16][40])(smem + 4112);  // 5120
  float (*sO)[4][16][16] = (float (*)[4][16][16])(smem + 9232);         // 16384
  float (*sM)[16] = (float (*)[16])(smem + 25616);                      // 256
  float (*sL)[16] = (float (*)[16])(smem + 25872);                      // 256
  const unsigned short* Qb = a.wsb + QB_OFF;
  const unsigned short* Kb = a.wsb + KB_OFF;
  const unsigned short* Vt = a.wsb + VT_OFF;
  int bh = b * 8 + h;
  int q0 = qt * 16;
  int tid = threadIdx.x, wave = tid >> 6, lane = tid & 63;
  int quad = lane >> 4, l16 = lane & 15;
  for (int i = tid; i < 513; i += 256) { sAh[i] = a.wsA[i * 8 + h]; sCh[i] = a.wsC[i * 8 + h]; }
  // Q A-fragments straight from global (all 4 waves read the same 2 KB; L1/L2 hit)
  const unsigned short* qp = Qb + ((size_t)bh * 512 + q0 + l16) * 64 + quad * 8;
  bf16x8 qf0 = *(const bf16x8*)qp;
  bf16x8 qf1 = *(const bf16x8*)(qp + 32);
  int key_base = wave * 128;
  // ---- S = Q@K^T for the wave's 128-key slice (no barriers) ----
  f32x4 S[4][2];
#pragma unroll
  for (int kt = 0; kt < 4; ++kt) {
    int key0 = key_base + kt * 32;
#pragma unroll
    for (int half = 0; half < 2; ++half) {
      const unsigned short* kp = Kb + ((size_t)bh * 512 + key0 + half * 16 + l16) * 64 + quad * 8;
      bf16x8 kf0 = *(const bf16x8*)kp;
      bf16x8 kf1 = *(const bf16x8*)(kp + 32);
      f32x4 acc = {0.f, 0.f, 0.f, 0.f};
      acc = __builtin_amdgcn_mfma_f32_16x16x32_bf16(qf0, kf0, acc, 0, 0, 0);
      acc = __builtin_amdgcn_mfma_f32_16x16x32_bf16(qf1, kf1, acc, 0, 0, 0);
      S[kt][half] = acc;
    }
  }
  __syncthreads();  // sAh/sCh ready (placed after MFMA issue to overlap)
  // ---- scale + exact PWL edge bias ----
#pragma unroll
  for (int kt = 0; kt < 4; ++kt)
#pragma unroll
    for (int half = 0; half < 2; ++half)
#pragma unroll
      for (int r = 0; r < 4; ++r) {
        int eidx = (b * 512 + q0 + quad * 4 + r) * 512 + key_base + kt * 32 + half * 16 + l16;
        float ev = a.eg[eidx];
        int sg = a.segp[eidx];
        S[kt][half][r] = S[kt][half][r] * 0.125f + sAh[sg] * ev + sCh[sg];
      }
  // ---- two-pass softmax on the wave's slice (rows live in 16-lane quads) ----
  float m_w[4], l_w[4];
#pragma unroll
  for (int r = 0; r < 4; ++r) {
    float mx = -3.4e38f;
#pragma unroll
    for (int kt = 0; kt < 4; ++kt) { mx = fmaxf(mx, fmaxf(S[kt][0][r], S[kt][1][r])); }
    for (int off = 1; off < 16; off <<= 1) mx = fmaxf(mx, __shfl_xor(mx, off, 64));
    float s = 0.f;
#pragma unroll
    for (int kt = 0; kt < 4; ++kt)
#pragma unroll
      for (int half = 0; half < 2; ++half) {
        float p = exp2f((S[kt][half][r] - mx) * LOG2E);
        S[kt][half][r] = p; s += p;
      }
    for (int off = 1; off < 16; off <<= 1) s += __shfl_xor(s, off, 64);
    m_w[r] = mx; l_w[r] = s;
  }
  // ---- PV over the slice: P C-layout -> A-layout via wave-private LDS ----
  f32x4 Oacc[4] = {{0.f,0.f,0.f,0.f},{0.f,0.f,0.f,0.f},{0.f,0.f,0.f,0.f},{0.f,0.f,0.f,0.f}};
#pragma unroll
  for (int kt = 0; kt < 4; ++kt) {
    int key0 = key_base + kt * 32;
#pragma unroll
    for (int half = 0; half < 2; ++half)
#pragma unroll
      for (int r = 0; r < 4; ++r)
        sP[wave][quad * 4 + r][half * 16 + l16] = f2bf(S[kt][half][r]);
    __builtin_amdgcn_wave_barrier();  // per-wave DS ops are in-order; fence compiler only
    bf16x8 pf = *(const bf16x8*)&sP[wave][l16][quad * 8];
    __builtin_amdgcn_wave_barrier();
#pragma unroll
    for (int nt = 0; nt < 4; ++nt) {
      bf16x8 vf = *(const bf16x8*)(Vt + ((size_t)bh * 64 + nt * 16 + l16) * 512 + key0 + quad * 8);
      Oacc[nt] = __builtin_amdgcn_mfma_f32_16x16x32_bf16(pf, vf, Oacc[nt], 0, 0, 0);
    }
  }
  // ---- combine the 4 wave-partials (flash rescale) ----
  if (l16 == 0) {
#pragma unroll
    for (int r = 0; r < 4; ++r) { sM[wave][quad * 4 + r] = m_w[r]; sL[wave][quad * 4 + r] = l_w[r]; }
  }
#pragma unroll
  for (int nt = 0; nt < 4; ++nt)
#pragma unroll
    for (int r = 0; r < 4; ++r)
      sO[wave][nt][quad * 4 + r][l16] = Oacc[nt][r];
  __syncthreads();
  // wave w finalizes d-chunk nt=w for all 16 rows
#pragma unroll
  for (int r = 0; r < 4; ++r) {
    int row = quad * 4 + r;
    float M = fmaxf(fmaxf(sM[0][row], sM[1][row]), fmaxf(sM[2][row], sM[3][row]));
    float L = 0.f, Ov = 0.f;
#pragma unroll
    for (int wv = 0; wv < 4; ++wv) {
      float f = exp2f((sM[wv][row] - M) * LOG2E);
      L += f * sL[wv][row];
      Ov += f * sO[wv][wave][row][l16];
    }
    float v = Ov / L;
    (a.wsb + AO_OFF)[((size_t)(b * 512 + q0 + row)) * 512 + h * 64 + wave * 16 + l16] = f2bf(v);
  }
}

// ---------------- phase dispatchers ----------------
__device__ void phase0(const MegaArgs& a, int blk, char* smem) {
  if (blk == 0) prep_block(a, smem);
  else if (blk <= 128) transpose2(a, blk - 1, smem);
  else convert_units(a, blk);
}
__device__ void phase1(const MegaArgs& a, int blk, char* smem) {
  if (blk < 384) {
    int z = blk >> 7, rem = blk & 127;
    const unsigned short* A  = a.wsb + ((z == 0) ? XQ_OFF : (z == 1) ? XK_OFF : XV_OFF);
    const unsigned short* Wt = a.wsb + ((z == 0) ? WQ_OFF : (z == 1) ? WK_OFF : WV_OFF);
    const float* bias = (z == 0) ? a.bq : (z == 1) ? a.bk : a.bv;
    void* outp = (void*)(a.wsb + ((z == 0) ? QB_OFF : (z == 1) ? KB_OFF : VT_OFF));
    gemm_tile(A, Wt, bias, outp, (z == 2) ? 2 : 0, (rem & 15) * 64, (rem >> 4) * 64, smem);
  } else {
    seg_block(a, blk - 384, smem);
  }
}

// ---------------- single cooperative launch: all phases ----------------
__global__ __launch_bounds__(256) void k_mega(MegaArgs a) {
  cg::grid_group grid = cg::this_grid();
  __shared__ __align__(16) char smem[SMEM_BYTES];
  int blk = blockIdx.x;
  phase0(a, blk, smem);
  grid.sync();
  phase1(a, blk, smem);
  grid.sync();
  attn_block(a, blk & 31, (blk >> 5) & 7, blk >> 8, smem);
  grid.sync();
  if (blk < 128)
    gemm_tile(a.wsb + AO_OFF, a.wsb + WO_OFF, a.bo, (void*)a.out, 1,
              (blk & 15) * 64, (blk >> 4) * 64, smem);
}

// ---------------- fallback: same device code, 4 plain launches ----------------
__global__ __launch_bounds__(256) void fb_p0(MegaArgs a) {
  __shared__ __align__(16) char smem[SMEM_BYTES];
  phase0(a, blockIdx.x, smem);
}
__global__ __launch_bounds__(256) void fb_p1(MegaArgs a) {
  __shared__ __align__(16) char smem[SMEM_BYTES];
  phase1(a, blockIdx.x, smem);
}
__global__ __launch_bounds__(256) void fb_p2(MegaArgs a) {
  __shared__ __align__(16) char smem[SMEM_BYTES];
  int blk = blockIdx.x;
  attn_block(a, blk & 31, (blk >> 5) & 7, blk >> 8, smem);
}
__global__ __launch_bounds__(256) void fb_p3(MegaArgs a) {
  __shared__ __align__(16) char smem[SMEM_BYTES];
  gemm_tile(a.wsb + AO_OFF, a.wsb + WO_OFF, a.bo, (void*)a.out, 1,
            (blockIdx.x & 15) * 64, (blockIdx.x >> 4) * 64, smem);
}

extern "C" void kernel_launch(void* const* d_in, const int* in_sizes, int n_in,
                              void* d_out, int out_size, void* d_ws, size_t ws_size,
                              hipStream_t stream) {
  MegaArgs a;
  a.xq  = (const float*)d_in[0];
  a.xk  = (const float*)d_in[1];
  a.xv  = (const float*)d_in[2];
  a.eg  = (const float*)d_in[3];
  a.wq  = (const float*)d_in[4];
  a.bq  = (const float*)d_in[5];
  a.wk  = (const float*)d_in[6];
  a.bk  = (const float*)d_in[7];
  a.wv  = (const float*)d_in[8];
  a.bv  = (const float*)d_in[9];
  a.wo  = (const float*)d_in[10];
  a.bo  = (const float*)d_in[11];
  a.w1  = (const float*)d_in[12];
  a.b1  = (const float*)d_in[13];
  a.we2 = (const float*)d_in[14];
  a.be2 = (const float*)d_in[15];
  a.out = (float*)d_out;
  a.wsb = (unsigned short*)d_ws;
  a.wsT = (float*)((char*)d_ws + T_B);
  a.wsA = (float*)((char*)d_ws + A_B);
  a.wsC = (float*)((char*)d_ws + C_B);
  a.segp = (unsigned short*)((char*)d_ws + SEG_B);

  void* kargs[] = { (void*)&a };
  hipError_t err = hipLaunchCooperativeKernel((const void*)k_mega, dim3(512), dim3(256),
                                              kargs, 0, stream);
  if (err != hipSuccess) {
    (void)hipGetLastError();  // clear sticky error; fall back to plain launches
    fb_p0<<<512, 256, 0, stream>>>(a);
    fb_p1<<<512, 256, 0, stream>>>(a);
    fb_p2<<<512, 256, 0, stream>>>(a);
    fb_p3<<<128, 256, 0, stream>>>(a);
  }
}

// Round 5
// 156.144 us; speedup vs baseline: 2.3051x; 2.3051x over previous
//
#include <hip/hip_runtime.h>
#include <hip/hip_bf16.h>

typedef __attribute__((ext_vector_type(8))) short bf16x8;
typedef __attribute__((ext_vector_type(4))) float f32x4;

#define LOG2E 1.44269504088896340736f

// ---- workspace layout ----
// bf16 element offsets
#define XQ_OFF 0
#define XK_OFF 524288
#define XV_OFF 1048576
#define WQ_OFF 1572864
#define WK_OFF 1835008
#define WV_OFF 2097152
#define WO_OFF 2359296
#define QB_OFF 2621440
#define KB_OFF 3145728
#define VT_OFF 3670016
#define AO_OFF 4194304
// byte offsets (fp32 tables / seg indices)
#define T_B   9437184
#define A_B   (T_B + 4096)
#define C_B   (A_B + 20480)
#define SEG_B (C_B + 20480)

struct MegaArgs {
  const float *xq, *xk, *xv, *eg;
  const float *wq, *wk, *wv, *wo;
  const float *bq, *bk, *bv, *bo;
  const float *w1, *b1, *we2, *be2;
  float* out;
  unsigned short* wsb;
  float *wsT, *wsA, *wsC;
  unsigned short* segp;
};

__device__ __forceinline__ unsigned short f2bf(float f) {
  union { __hip_bfloat16 h; unsigned short u; } c;
  c.h = __float2bfloat16(f);
  return c.u;
}

// ---------------- edge-MLP -> exact PWL tables (1 block, 256 threads) ----------------
// f_h(e) = sum_k We2[k,h]*relu(e*w1[k]+b1[k]) + be2[h] is PWL with breakpoints t_k=-b1/w1.
__device__ void prep_block(const MegaArgs& a, char* smem) {
  float* sT   = (float*)smem;                      // 2048
  int*   sIdx = (int*)(smem + 2048);               // 2048
  float (*sDA)[8] = (float (*)[8])(smem + 4096);   // 16384
  float (*sDC)[8] = (float (*)[8])(smem + 20480);  // 16384
  float* sA0 = (float*)(smem + 36864);             // 32
  float* sC0 = (float*)(smem + 36896);             // 32
  int tid = threadIdx.x;
  for (int p = tid; p < 512; p += 256) {
    float w = a.w1[p], bb = a.b1[p];
    sT[p] = (w != 0.f) ? (-bb / w) : -3.4e38f;  // w==0: never a real crossing
    sIdx[p] = p;
    // seg-0 contributions (active set = {k : w1[k] < 0}; w==0 contributes const relu(b))
#pragma unroll
    for (int h = 0; h < 8; ++h) {
      float w2 = a.we2[p * 8 + h];
      float ra = 0.f, rc = 0.f;
      if (w < 0.f)       { ra = w2 * w; rc = w2 * bb; }
      else if (w == 0.f) { rc = w2 * fmaxf(bb, 0.f); }
      sDA[p][h] = ra; sDC[p][h] = rc;
    }
  }
  __syncthreads();
  // bitonic sort ascending: 256 compare-exchange pairs per substage
  for (int size = 2; size <= 512; size <<= 1) {
    for (int stride = size >> 1; stride > 0; stride >>= 1) {
      int p = tid;
      int i = ((p / stride) * (stride << 1)) + (p % stride);
      int j = i + stride;
      bool up = ((i & size) == 0);
      float ti = sT[i], tj = sT[j];
      if (up ? (ti > tj) : (ti < tj)) {
        sT[i] = tj; sT[j] = ti;
        int t = sIdx[i]; sIdx[i] = sIdx[j]; sIdx[j] = t;
      }
      __syncthreads();
    }
  }
  // tree-reduce seg0 contributions (order-independent of the sort)
#pragma unroll
  for (int h = 0; h < 8; ++h) { sDA[tid][h] += sDA[tid + 256][h]; sDC[tid][h] += sDC[tid + 256][h]; }
  __syncthreads();
  for (int st = 128; st > 0; st >>= 1) {
    if (tid < st) {
#pragma unroll
      for (int h = 0; h < 8; ++h) { sDA[tid][h] += sDA[tid + st][h]; sDC[tid][h] += sDC[tid + st][h]; }
    }
    __syncthreads();
  }
  if (tid < 8) { sA0[tid] = sDA[0][tid]; sC0[tid] = sDC[0][tid] + a.be2[tid]; }
  __syncthreads();
  // per-sorted-position deltas
  for (int p = tid; p < 512; p += 256) {
    int k = sIdx[p];
    float wk = a.w1[k], bk2 = a.b1[k];
#pragma unroll
    for (int h = 0; h < 8; ++h) {
      float w2 = a.we2[k * 8 + h];
      float da = 0.f, dc = 0.f;
      if (wk > 0.f)      { da =  w2 * wk; dc =  w2 * bk2; }
      else if (wk < 0.f) { da = -w2 * wk; dc = -w2 * bk2; }
      sDA[p][h] = da; sDC[p][h] = dc;
    }
  }
  __syncthreads();
  // inclusive Hillis-Steele scan over 512 sorted positions, 2 per thread
  for (int off = 1; off < 512; off <<= 1) {
    float ra[2][8], rc[2][8];
#pragma unroll
    for (int e = 0; e < 2; ++e) {
      int p = tid + e * 256;
      if (p >= off) {
#pragma unroll
        for (int h = 0; h < 8; ++h) { ra[e][h] = sDA[p - off][h]; rc[e][h] = sDC[p - off][h]; }
      }
    }
    __syncthreads();
#pragma unroll
    for (int e = 0; e < 2; ++e) {
      int p = tid + e * 256;
      if (p >= off) {
#pragma unroll
        for (int h = 0; h < 8; ++h) { sDA[p][h] += ra[e][h]; sDC[p][h] += rc[e][h]; }
      }
    }
    __syncthreads();
  }
  a.wsT[tid] = sT[tid]; a.wsT[tid + 256] = sT[tid + 256];
  if (tid < 8) { a.wsA[tid] = sA0[tid]; a.wsC[tid] = sC0[tid]; }
  for (int p = tid; p < 512; p += 256) {
#pragma unroll
    for (int h = 0; h < 8; ++h) {
      a.wsA[(p + 1) * 8 + h] = sA0[h] + sDA[p][h];
      a.wsC[(p + 1) * 8 + h] = sC0[h] + sDC[p][h];
    }
  }
}

// ---------------- two 64x64 weight-transpose tiles (LDS-staged, coalesced) ------------
__device__ void transpose2(const MegaArgs& a, int tblk, char* smem) {
  unsigned short (*sWt)[72] = (unsigned short (*)[72])smem;
  int tid = threadIdx.x;
  for (int it = 0; it < 2; ++it) {
    int t = tblk * 2 + it;
    int mat = t >> 6, tile = t & 63;
    int k0 = (tile >> 3) * 64, n0 = (tile & 7) * 64;
    const float* src = (mat == 0) ? a.wq : (mat == 1) ? a.wk : (mat == 2) ? a.wv : a.wo;
    int row = tid >> 2, cq = tid & 3;
    const float4* sp = (const float4*)(src + (size_t)(k0 + row) * 512 + n0 + cq * 16);
    if (it) __syncthreads();
#pragma unroll
    for (int j2 = 0; j2 < 4; ++j2) {
      float4 v = sp[j2];
      int nl = cq * 16 + j2 * 4;
      sWt[nl + 0][row] = f2bf(v.x);
      sWt[nl + 1][row] = f2bf(v.y);
      sWt[nl + 2][row] = f2bf(v.z);
      sWt[nl + 3][row] = f2bf(v.w);
    }
    __syncthreads();
    int n = tid >> 2, kq = tid & 3;
    unsigned short* dst = a.wsb + WQ_OFF + mat * 262144 + (size_t)(n0 + n) * 512 + k0 + kq * 16;
    *(uint4*)dst       = *(const uint4*)&sWt[n][kq * 16];
    *(uint4*)(dst + 8) = *(const uint4*)&sWt[n][kq * 16 + 8];
  }
}

// ---------------- x fp32->bf16 convert, grid-strided units of 256 float4 --------------
__device__ void convert_units(const MegaArgs& a, int blk) {
  int tid = threadIdx.x;
  for (int u = blk - 129; u < 1536; u += 383) {
    int i = u * 256 + tid;
    int region = i >> 17, off = i & 131071;
    const float* src = (region == 0) ? a.xq : (region == 1) ? a.xk : a.xv;
    float4 v = ((const float4*)src)[off];
    ushort4 o;
    o.x = f2bf(v.x); o.y = f2bf(v.y); o.z = f2bf(v.z); o.w = f2bf(v.w);
    ((ushort4*)a.wsb)[i] = o;
  }
}

// ---------------- per-edge segment index (binary search over sorted breakpoints) ------
__device__ void seg_block(const MegaArgs& a, int sblk, char* smem) {
  float* sT = (float*)smem;
  int tid = threadIdx.x;
  sT[tid] = a.wsT[tid]; sT[tid + 256] = a.wsT[tid + 256];
  __syncthreads();
  int base = sblk * 4096;
  for (int j2 = 0; j2 < 16; ++j2) {
    int i = base + j2 * 256 + tid;
    float ev = a.eg[i];
    int lo = 0, hi = 512;
    while (lo < hi) {  // count of T[s] < ev
      int mid = (lo + hi) >> 1;
      if (sT[mid] < ev) lo = mid + 1; else hi = mid;
    }
    a.segp[i] = (unsigned short)lo;
  }
}

// ---------------- bf16 MFMA GEMM tile: Y = X @ Wt^T + bias (64x64, K=512) -------------
__device__ void gemm_tile(const unsigned short* __restrict__ A, const unsigned short* __restrict__ Wt,
                          const float* __restrict__ bias, void* out, int mode,
                          int m0, int n0, char* smem) {
  const int K = 512;
  unsigned short (*sA)[72]  = (unsigned short (*)[72])smem;
  unsigned short (*sBt)[72] = (unsigned short (*)[72])(smem + 9216);
  int tid = threadIdx.x, wave = tid >> 6, lane = tid & 63;
  int quad = lane >> 4, l16 = lane & 15;
  f32x4 acc[4] = {{0.f,0.f,0.f,0.f},{0.f,0.f,0.f,0.f},{0.f,0.f,0.f,0.f},{0.f,0.f,0.f,0.f}};
  int lr = tid >> 2, ls = tid & 3;
  for (int kb = 0; kb < K; kb += 64) {
    __syncthreads();
    *(uint4*)&sA[lr][ls * 16]      = *(const uint4*)(A  + (size_t)(m0 + lr) * K + kb + ls * 16);
    *(uint4*)&sA[lr][ls * 16 + 8]  = *(const uint4*)(A  + (size_t)(m0 + lr) * K + kb + ls * 16 + 8);
    *(uint4*)&sBt[lr][ls * 16]     = *(const uint4*)(Wt + (size_t)(n0 + lr) * K + kb + ls * 16);
    *(uint4*)&sBt[lr][ls * 16 + 8] = *(const uint4*)(Wt + (size_t)(n0 + lr) * K + kb + ls * 16 + 8);
    __syncthreads();
    for (int ks = 0; ks < 2; ++ks) {
      bf16x8 af = *(const bf16x8*)&sA[wave * 16 + l16][ks * 32 + quad * 8];
#pragma unroll
      for (int nt = 0; nt < 4; ++nt) {
        bf16x8 bf = *(const bf16x8*)&sBt[nt * 16 + l16][ks * 32 + quad * 8];
        acc[nt] = __builtin_amdgcn_mfma_f32_16x16x32_bf16(af, bf, acc[nt], 0, 0, 0);
      }
    }
  }
  int mbase = m0 + wave * 16 + quad * 4;  // C row = quad*4+reg (m89-verified)
#pragma unroll
  for (int nt = 0; nt < 4; ++nt) {
    int n = n0 + nt * 16 + l16;
    float bv = bias[n];
#pragma unroll
    for (int r = 0; r < 4; ++r) {
      float v = acc[nt][r] + bv;
      int m = mbase + r;
      if (mode == 0) {
        int b = m >> 9, l = m & 511, hh = n >> 6, d = n & 63;
        ((unsigned short*)out)[(((size_t)(b * 8 + hh) * 512) + l) * 64 + d] = f2bf(v);
      } else if (mode == 1) {
        ((float*)out)[(size_t)m * 512 + n] = v;
      } else {
        int b = m >> 9, l = m & 511, hh = n >> 6, d = n & 63;
        ((unsigned short*)out)[(((size_t)(b * 8 + hh) * 64) + d) * 512 + l] = f2bf(v);
      }
    }
  }
}

// ---------------- fused edge-bias attention (16 q-rows/block, waves split keys) -------
__device__ void attn_block(const MegaArgs& a, int qt, int h, int b, char* smem) {
  float* sAh = (float*)smem;                                            // 2052
  float* sCh = (float*)(smem + 2052);                                   // 2052
  unsigned short (*sP)[16][40] = (unsigned short (*)[16][40])(smem + 4112);  // 5120
  float (*sO)[4][16][16] = (float (*)[4][16][16])(smem + 9232);         // 16384
  float (*sM)[16] = (float (*)[16])(smem + 25616);                      // 256
  float (*sL)[16] = (float (*)[16])(smem + 25872);                      // 256
  const unsigned short* Qb = a.wsb + QB_OFF;
  const unsigned short* Kb = a.wsb + KB_OFF;
  const unsigned short* Vt = a.wsb + VT_OFF;
  int bh = b * 8 + h;
  int q0 = qt * 16;
  int tid = threadIdx.x, wave = tid >> 6, lane = tid & 63;
  int quad = lane >> 4, l16 = lane & 15;
  for (int i = tid; i < 513; i += 256) { sAh[i] = a.wsA[i * 8 + h]; sCh[i] = a.wsC[i * 8 + h]; }
  // Q A-fragments straight from global (all 4 waves read the same 2 KB; L1/L2 hit)
  const unsigned short* qp = Qb + ((size_t)bh * 512 + q0 + l16) * 64 + quad * 8;
  bf16x8 qf0 = *(const bf16x8*)qp;
  bf16x8 qf1 = *(const bf16x8*)(qp + 32);
  int key_base = wave * 128;
  // ---- S = Q@K^T for the wave's 128-key slice (no barriers) ----
  f32x4 S[4][2];
#pragma unroll
  for (int kt = 0; kt < 4; ++kt) {
    int key0 = key_base + kt * 32;
#pragma unroll
    for (int half = 0; half < 2; ++half) {
      const unsigned short* kp = Kb + ((size_t)bh * 512 + key0 + half * 16 + l16) * 64 + quad * 8;
      bf16x8 kf0 = *(const bf16x8*)kp;
      bf16x8 kf1 = *(const bf16x8*)(kp + 32);
      f32x4 acc = {0.f, 0.f, 0.f, 0.f};
      acc = __builtin_amdgcn_mfma_f32_16x16x32_bf16(qf0, kf0, acc, 0, 0, 0);
      acc = __builtin_amdgcn_mfma_f32_16x16x32_bf16(qf1, kf1, acc, 0, 0, 0);
      S[kt][half] = acc;
    }
  }
  __syncthreads();  // sAh/sCh ready (placed after MFMA issue to overlap)
  // ---- scale + exact PWL edge bias ----
#pragma unroll
  for (int kt = 0; kt < 4; ++kt)
#pragma unroll
    for (int half = 0; half < 2; ++half)
#pragma unroll
      for (int r = 0; r < 4; ++r) {
        int eidx = (b * 512 + q0 + quad * 4 + r) * 512 + key_base + kt * 32 + half * 16 + l16;
        float ev = a.eg[eidx];
        int sg = a.segp[eidx];
        S[kt][half][r] = S[kt][half][r] * 0.125f + sAh[sg] * ev + sCh[sg];
      }
  // ---- two-pass softmax on the wave's slice (rows live in 16-lane quads) ----
  float m_w[4], l_w[4];
#pragma unroll
  for (int r = 0; r < 4; ++r) {
    float mx = -3.4e38f;
#pragma unroll
    for (int kt = 0; kt < 4; ++kt) { mx = fmaxf(mx, fmaxf(S[kt][0][r], S[kt][1][r])); }
    for (int off = 1; off < 16; off <<= 1) mx = fmaxf(mx, __shfl_xor(mx, off, 64));
    float s = 0.f;
#pragma unroll
    for (int kt = 0; kt < 4; ++kt)
#pragma unroll
      for (int half = 0; half < 2; ++half) {
        float p = exp2f((S[kt][half][r] - mx) * LOG2E);
        S[kt][half][r] = p; s += p;
      }
    for (int off = 1; off < 16; off <<= 1) s += __shfl_xor(s, off, 64);
    m_w[r] = mx; l_w[r] = s;
  }
  // ---- PV over the slice: P C-layout -> A-layout via wave-private LDS ----
  f32x4 Oacc[4] = {{0.f,0.f,0.f,0.f},{0.f,0.f,0.f,0.f},{0.f,0.f,0.f,0.f},{0.f,0.f,0.f,0.f}};
#pragma unroll
  for (int kt = 0; kt < 4; ++kt) {
    int key0 = key_base + kt * 32;
#pragma unroll
    for (int half = 0; half < 2; ++half)
#pragma unroll
      for (int r = 0; r < 4; ++r)
        sP[wave][quad * 4 + r][half * 16 + l16] = f2bf(S[kt][half][r]);
    __builtin_amdgcn_wave_barrier();  // per-wave DS ops are in-order; fence compiler only
    bf16x8 pf = *(const bf16x8*)&sP[wave][l16][quad * 8];
    __builtin_amdgcn_wave_barrier();
#pragma unroll
    for (int nt = 0; nt < 4; ++nt) {
      bf16x8 vf = *(const bf16x8*)(Vt + ((size_t)bh * 64 + nt * 16 + l16) * 512 + key0 + quad * 8);
      Oacc[nt] = __builtin_amdgcn_mfma_f32_16x16x32_bf16(pf, vf, Oacc[nt], 0, 0, 0);
    }
  }
  // ---- combine the 4 wave-partials (flash rescale) ----
  if (l16 == 0) {
#pragma unroll
    for (int r = 0; r < 4; ++r) { sM[wave][quad * 4 + r] = m_w[r]; sL[wave][quad * 4 + r] = l_w[r]; }
  }
#pragma unroll
  for (int nt = 0; nt < 4; ++nt)
#pragma unroll
    for (int r = 0; r < 4; ++r)
      sO[wave][nt][quad * 4 + r][l16] = Oacc[nt][r];
  __syncthreads();
  // wave w finalizes d-chunk nt=w for all 16 rows
#pragma unroll
  for (int r = 0; r < 4; ++r) {
    int row = quad * 4 + r;
    float M = fmaxf(fmaxf(sM[0][row], sM[1][row]), fmaxf(sM[2][row], sM[3][row]));
    float L = 0.f, Ov = 0.f;
#pragma unroll
    for (int wv = 0; wv < 4; ++wv) {
      float f = exp2f((sM[wv][row] - M) * LOG2E);
      L += f * sL[wv][row];
      Ov += f * sO[wv][wave][row][l16];
    }
    float v = Ov / L;
    (a.wsb + AO_OFF)[((size_t)(b * 512 + q0 + row)) * 512 + h * 64 + wave * 16 + l16] = f2bf(v);
  }
}

// ---------------- launch 1: prep (block 0) + weight transpose + x convert ----------------
__global__ __launch_bounds__(256) void k_pre(MegaArgs a) {
  __shared__ __align__(16) char smem[36928];
  int blk = blockIdx.x;
  if (blk == 0) prep_block(a, smem);
  else if (blk <= 128) transpose2(a, blk - 1, smem);
  else convert_units(a, blk);
}

// ---------------- launch 2: QKV GEMM (384 blocks) + edge seg index (128 blocks) ----------------
__global__ __launch_bounds__(256) void k_qkv(MegaArgs a) {
  __shared__ __align__(16) char smem[18432];
  int blk = blockIdx.x;
  if (blk < 384) {
    int z = blk >> 7, rem = blk & 127;
    const unsigned short* A  = a.wsb + ((z == 0) ? XQ_OFF : (z == 1) ? XK_OFF : XV_OFF);
    const unsigned short* Wt = a.wsb + ((z == 0) ? WQ_OFF : (z == 1) ? WK_OFF : WV_OFF);
    const float* bias = (z == 0) ? a.bq : (z == 1) ? a.bk : a.bv;
    void* outp = (void*)(a.wsb + ((z == 0) ? QB_OFF : (z == 1) ? KB_OFF : VT_OFF));
    gemm_tile(A, Wt, bias, outp, (z == 2) ? 2 : 0, (rem & 15) * 64, (rem >> 4) * 64, smem);
  } else {
    seg_block(a, blk - 384, smem);
  }
}

// ---------------- launch 3: attention ----------------
__global__ __launch_bounds__(256) void k_at(MegaArgs a) {
  __shared__ __align__(16) char smem[26128];
  int blk = blockIdx.x;
  attn_block(a, blk & 31, (blk >> 5) & 7, blk >> 8, smem);
}

// ---------------- launch 4: output GEMM ----------------
__global__ __launch_bounds__(256) void k_og(MegaArgs a) {
  __shared__ __align__(16) char smem[18432];
  gemm_tile(a.wsb + AO_OFF, a.wsb + WO_OFF, a.bo, (void*)a.out, 1,
            (blockIdx.x & 15) * 64, (blockIdx.x >> 4) * 64, smem);
}

extern "C" void kernel_launch(void* const* d_in, const int* in_sizes, int n_in,
                              void* d_out, int out_size, void* d_ws, size_t ws_size,
                              hipStream_t stream) {
  MegaArgs a;
  a.xq  = (const float*)d_in[0];
  a.xk  = (const float*)d_in[1];
  a.xv  = (const float*)d_in[2];
  a.eg  = (const float*)d_in[3];
  a.wq  = (const float*)d_in[4];
  a.bq  = (const float*)d_in[5];
  a.wk  = (const float*)d_in[6];
  a.bk  = (const float*)d_in[7];
  a.wv  = (const float*)d_in[8];
  a.bv  = (const float*)d_in[9];
  a.wo  = (const float*)d_in[10];
  a.bo  = (const float*)d_in[11];
  a.w1  = (const float*)d_in[12];
  a.b1  = (const float*)d_in[13];
  a.we2 = (const float*)d_in[14];
  a.be2 = (const float*)d_in[15];
  a.out = (float*)d_out;
  a.wsb = (unsigned short*)d_ws;
  a.wsT = (float*)((char*)d_ws + T_B);
  a.wsA = (float*)((char*)d_ws + A_B);
  a.wsC = (float*)((char*)d_ws + C_B);
  a.segp = (unsigned short*)((char*)d_ws + SEG_B);

  k_pre<<<512, 256, 0, stream>>>(a);
  k_qkv<<<512, 256, 0, stream>>>(a);
  k_at<<<512, 256, 0, stream>>>(a);
  k_og<<<128, 256, 0, stream>>>(a);
}

// Round 6
// 141.755 us; speedup vs baseline: 2.5391x; 1.1015x over previous
//
#include <hip/hip_runtime.h>
#include <hip/hip_bf16.h>

typedef __attribute__((ext_vector_type(8))) short bf16x8;
typedef __attribute__((ext_vector_type(4))) float f32x4;

#define LOG2E 1.44269504088896340736f

// ---- workspace layout ----
// bf16 element offsets
#define XQ_OFF 0
#define XK_OFF 524288
#define XV_OFF 1048576
#define WQ_OFF 1572864
#define WK_OFF 1835008
#define WV_OFF 2097152
#define WO_OFF 2359296
#define QB_OFF 2621440
#define KB_OFF 3145728
#define VT_OFF 3670016
#define AO_OFF 4194304
// byte offsets (fp32 tables / seg indices)
#define T_B   9437184
#define A_B   (T_B + 4096)
#define C_B   (A_B + 20480)
#define SEG_B (C_B + 20480)

struct MegaArgs {
  const float *xq, *xk, *xv, *eg;
  const float *wq, *wk, *wv, *wo;
  const float *bq, *bk, *bv, *bo;
  const float *w1, *b1, *we2, *be2;
  float* out;
  unsigned short* wsb;
  float *wsT, *wsA, *wsC;   // wsA/wsC stored [h][513] for coalesced attn loads
  unsigned short* segp;
};

__device__ __forceinline__ unsigned short f2bf(float f) {
  union { __hip_bfloat16 h; unsigned short u; } c;
  c.h = __float2bfloat16(f);
  return c.u;
}

// ---------------- edge-MLP -> exact PWL tables (1 block, 256 threads) ----------------
// f_h(e) = sum_k We2[k,h]*relu(e*w1[k]+b1[k]) + be2[h] is PWL with breakpoints t_k=-b1/w1.
__device__ void prep_block(const MegaArgs& a, char* smem) {
  float* sT   = (float*)smem;                      // 2048
  int*   sIdx = (int*)(smem + 2048);               // 2048
  float (*sDA)[8] = (float (*)[8])(smem + 4096);   // 16384
  float (*sDC)[8] = (float (*)[8])(smem + 20480);  // 16384
  float* sA0 = (float*)(smem + 36864);             // 32
  float* sC0 = (float*)(smem + 36896);             // 32
  int tid = threadIdx.x;
  for (int p = tid; p < 512; p += 256) {
    float w = a.w1[p], bb = a.b1[p];
    sT[p] = (w != 0.f) ? (-bb / w) : -3.4e38f;  // w==0: never a real crossing
    sIdx[p] = p;
    // seg-0 contributions (active set = {k : w1[k] < 0}; w==0 contributes const relu(b))
#pragma unroll
    for (int h = 0; h < 8; ++h) {
      float w2 = a.we2[p * 8 + h];
      float ra = 0.f, rc = 0.f;
      if (w < 0.f)       { ra = w2 * w; rc = w2 * bb; }
      else if (w == 0.f) { rc = w2 * fmaxf(bb, 0.f); }
      sDA[p][h] = ra; sDC[p][h] = rc;
    }
  }
  __syncthreads();
  // bitonic sort ascending: 256 compare-exchange pairs per substage
  for (int size = 2; size <= 512; size <<= 1) {
    for (int stride = size >> 1; stride > 0; stride >>= 1) {
      int p = tid;
      int i = ((p / stride) * (stride << 1)) + (p % stride);
      int j = i + stride;
      bool up = ((i & size) == 0);
      float ti = sT[i], tj = sT[j];
      if (up ? (ti > tj) : (ti < tj)) {
        sT[i] = tj; sT[j] = ti;
        int t = sIdx[i]; sIdx[i] = sIdx[j]; sIdx[j] = t;
      }
      __syncthreads();
    }
  }
  // tree-reduce seg0 contributions (order-independent of the sort)
#pragma unroll
  for (int h = 0; h < 8; ++h) { sDA[tid][h] += sDA[tid + 256][h]; sDC[tid][h] += sDC[tid + 256][h]; }
  __syncthreads();
  for (int st = 128; st > 0; st >>= 1) {
    if (tid < st) {
#pragma unroll
      for (int h = 0; h < 8; ++h) { sDA[tid][h] += sDA[tid + st][h]; sDC[tid][h] += sDC[tid + st][h]; }
    }
    __syncthreads();
  }
  if (tid < 8) { sA0[tid] = sDA[0][tid]; sC0[tid] = sDC[0][tid] + a.be2[tid]; }
  __syncthreads();
  // per-sorted-position deltas
  for (int p = tid; p < 512; p += 256) {
    int k = sIdx[p];
    float wk = a.w1[k], bk2 = a.b1[k];
#pragma unroll
    for (int h = 0; h < 8; ++h) {
      float w2 = a.we2[k * 8 + h];
      float da = 0.f, dc = 0.f;
      if (wk > 0.f)      { da =  w2 * wk; dc =  w2 * bk2; }
      else if (wk < 0.f) { da = -w2 * wk; dc = -w2 * bk2; }
      sDA[p][h] = da; sDC[p][h] = dc;
    }
  }
  __syncthreads();
  // inclusive Hillis-Steele scan over 512 sorted positions, 2 per thread
  for (int off = 1; off < 512; off <<= 1) {
    float ra[2][8], rc[2][8];
#pragma unroll
    for (int e = 0; e < 2; ++e) {
      int p = tid + e * 256;
      if (p >= off) {
#pragma unroll
        for (int h = 0; h < 8; ++h) { ra[e][h] = sDA[p - off][h]; rc[e][h] = sDC[p - off][h]; }
      }
    }
    __syncthreads();
#pragma unroll
    for (int e = 0; e < 2; ++e) {
      int p = tid + e * 256;
      if (p >= off) {
#pragma unroll
        for (int h = 0; h < 8; ++h) { sDA[p][h] += ra[e][h]; sDC[p][h] += rc[e][h]; }
      }
    }
    __syncthreads();
  }
  a.wsT[tid] = sT[tid]; a.wsT[tid + 256] = sT[tid + 256];
  // tables stored [h][513]: coalesced per-head loads in attn
  if (tid < 8) { a.wsA[tid * 513] = sA0[tid]; a.wsC[tid * 513] = sC0[tid]; }
  for (int p = tid; p < 512; p += 256) {
#pragma unroll
    for (int h = 0; h < 8; ++h) {
      a.wsA[h * 513 + p + 1] = sA0[h] + sDA[p][h];
      a.wsC[h * 513 + p + 1] = sC0[h] + sDC[p][h];
    }
  }
}

// ---------------- two 64x64 weight-transpose tiles (LDS-staged, coalesced) ------------
__device__ void transpose2(const MegaArgs& a, int tblk, char* smem) {
  unsigned short (*sWt)[72] = (unsigned short (*)[72])smem;
  int tid = threadIdx.x;
  for (int it = 0; it < 2; ++it) {
    int t = tblk * 2 + it;
    int mat = t >> 6, tile = t & 63;
    int k0 = (tile >> 3) * 64, n0 = (tile & 7) * 64;
    const float* src = (mat == 0) ? a.wq : (mat == 1) ? a.wk : (mat == 2) ? a.wv : a.wo;
    int row = tid >> 2, cq = tid & 3;
    const float4* sp = (const float4*)(src + (size_t)(k0 + row) * 512 + n0 + cq * 16);
    if (it) __syncthreads();
#pragma unroll
    for (int j2 = 0; j2 < 4; ++j2) {
      float4 v = sp[j2];
      int nl = cq * 16 + j2 * 4;
      sWt[nl + 0][row] = f2bf(v.x);
      sWt[nl + 1][row] = f2bf(v.y);
      sWt[nl + 2][row] = f2bf(v.z);
      sWt[nl + 3][row] = f2bf(v.w);
    }
    __syncthreads();
    int n = tid >> 2, kq = tid & 3;
    unsigned short* dst = a.wsb + WQ_OFF + mat * 262144 + (size_t)(n0 + n) * 512 + k0 + kq * 16;
    *(uint4*)dst       = *(const uint4*)&sWt[n][kq * 16];
    *(uint4*)(dst + 8) = *(const uint4*)&sWt[n][kq * 16 + 8];
  }
}

// ---------------- per-edge segment index: fixed 9-step branchless lower-bound ---------
__device__ void seg_block(const MegaArgs& a, int sblk, char* smem) {
  float* sT = (float*)smem;
  int tid = threadIdx.x;
  sT[tid] = a.wsT[tid]; sT[tid + 256] = a.wsT[tid + 256];
  __syncthreads();
  int base = sblk * 1024;
  float ev[4];
#pragma unroll
  for (int j = 0; j < 4; ++j) ev[j] = a.eg[base + j * 256 + tid];
  int res[4];
#pragma unroll
  for (int j = 0; j < 4; ++j) {
    int lo = 0, hi = 512;
#pragma unroll
    for (int it = 0; it < 9; ++it) {  // 512-wide range: exactly 9 halvings
      int mid = (lo + hi) >> 1;
      bool c = sT[mid] < ev[j];
      lo = c ? mid + 1 : lo;
      hi = c ? hi : mid;
    }
    res[j] = lo;
  }
#pragma unroll
  for (int j = 0; j < 4; ++j) a.segp[base + j * 256 + tid] = (unsigned short)res[j];
}

// ---------------- bf16 MFMA GEMM tile: Y = X @ Wt^T + bias (64x64, K=512) -------------
__device__ void gemm_tile(const unsigned short* __restrict__ A, const unsigned short* __restrict__ Wt,
                          const float* __restrict__ bias, void* out, int mode,
                          int m0, int n0, char* smem) {
  const int K = 512;
  unsigned short (*sA)[72]  = (unsigned short (*)[72])smem;
  unsigned short (*sBt)[72] = (unsigned short (*)[72])(smem + 9216);
  int tid = threadIdx.x, wave = tid >> 6, lane = tid & 63;
  int quad = lane >> 4, l16 = lane & 15;
  f32x4 acc[4] = {{0.f,0.f,0.f,0.f},{0.f,0.f,0.f,0.f},{0.f,0.f,0.f,0.f},{0.f,0.f,0.f,0.f}};
  int lr = tid >> 2, ls = tid & 3;
  for (int kb = 0; kb < K; kb += 64) {
    __syncthreads();
    *(uint4*)&sA[lr][ls * 16]      = *(const uint4*)(A  + (size_t)(m0 + lr) * K + kb + ls * 16);
    *(uint4*)&sA[lr][ls * 16 + 8]  = *(const uint4*)(A  + (size_t)(m0 + lr) * K + kb + ls * 16 + 8);
    *(uint4*)&sBt[lr][ls * 16]     = *(const uint4*)(Wt + (size_t)(n0 + lr) * K + kb + ls * 16);
    *(uint4*)&sBt[lr][ls * 16 + 8] = *(const uint4*)(Wt + (size_t)(n0 + lr) * K + kb + ls * 16 + 8);
    __syncthreads();
    for (int ks = 0; ks < 2; ++ks) {
      bf16x8 af = *(const bf16x8*)&sA[wave * 16 + l16][ks * 32 + quad * 8];
#pragma unroll
      for (int nt = 0; nt < 4; ++nt) {
        bf16x8 bf = *(const bf16x8*)&sBt[nt * 16 + l16][ks * 32 + quad * 8];
        acc[nt] = __builtin_amdgcn_mfma_f32_16x16x32_bf16(af, bf, acc[nt], 0, 0, 0);
      }
    }
  }
  int mbase = m0 + wave * 16 + quad * 4;  // C row = quad*4+reg (m89-verified)
#pragma unroll
  for (int nt = 0; nt < 4; ++nt) {
    int n = n0 + nt * 16 + l16;
    float bv = bias[n];
#pragma unroll
    for (int r = 0; r < 4; ++r) {
      float v = acc[nt][r] + bv;
      int m = mbase + r;
      if (mode == 0) {
        int b = m >> 9, l = m & 511, hh = n >> 6, d = n & 63;
        ((unsigned short*)out)[(((size_t)(b * 8 + hh) * 512) + l) * 64 + d] = f2bf(v);
      } else if (mode == 1) {
        ((float*)out)[(size_t)m * 512 + n] = v;
      } else {
        int b = m >> 9, l = m & 511, hh = n >> 6, d = n & 63;
        ((unsigned short*)out)[(((size_t)(b * 8 + hh) * 64) + d) * 512 + l] = f2bf(v);
      }
    }
  }
}

// ---------------- fused edge-bias attention (16 q-rows/block, waves split keys) -------
__device__ void attn_block(const MegaArgs& a, int qt, int h, int b, char* smem) {
  float* sAh = (float*)smem;                                            // 2052
  float* sCh = (float*)(smem + 2052);                                   // 2052
  unsigned short (*sP)[16][40] = (unsigned short (*)[16][40])(smem + 4112);  // 5120
  float (*sO)[4][16][16] = (float (*)[4][16][16])(smem + 9232);         // 16384
  float (*sM)[16] = (float (*)[16])(smem + 25616);                      // 256
  float (*sL)[16] = (float (*)[16])(smem + 25872);                      // 256
  const unsigned short* Qb = a.wsb + QB_OFF;
  const unsigned short* Kb = a.wsb + KB_OFF;
  const unsigned short* Vt = a.wsb + VT_OFF;
  int bh = b * 8 + h;
  int q0 = qt * 16;
  int tid = threadIdx.x, wave = tid >> 6, lane = tid & 63;
  int quad = lane >> 4, l16 = lane & 15;
  // coalesced per-head table load ([h][513] layout)
  for (int i = tid; i < 513; i += 256) { sAh[i] = a.wsA[h * 513 + i]; sCh[i] = a.wsC[h * 513 + i]; }
  // Q A-fragments straight from global (all 4 waves read the same 2 KB; L1/L2 hit)
  const unsigned short* qp = Qb + ((size_t)bh * 512 + q0 + l16) * 64 + quad * 8;
  bf16x8 qf0 = *(const bf16x8*)qp;
  bf16x8 qf1 = *(const bf16x8*)(qp + 32);
  int key_base = wave * 128;
  // ---- S = Q@K^T for the wave's 128-key slice (no barriers) ----
  f32x4 S[4][2];
#pragma unroll
  for (int kt = 0; kt < 4; ++kt) {
    int key0 = key_base + kt * 32;
#pragma unroll
    for (int half = 0; half < 2; ++half) {
      const unsigned short* kp = Kb + ((size_t)bh * 512 + key0 + half * 16 + l16) * 64 + quad * 8;
      bf16x8 kf0 = *(const bf16x8*)kp;
      bf16x8 kf1 = *(const bf16x8*)(kp + 32);
      f32x4 acc = {0.f, 0.f, 0.f, 0.f};
      acc = __builtin_amdgcn_mfma_f32_16x16x32_bf16(qf0, kf0, acc, 0, 0, 0);
      acc = __builtin_amdgcn_mfma_f32_16x16x32_bf16(qf1, kf1, acc, 0, 0, 0);
      S[kt][half] = acc;
    }
  }
  __syncthreads();  // sAh/sCh ready (placed after MFMA issue to overlap)
  // ---- scale + exact PWL edge bias ----
#pragma unroll
  for (int kt = 0; kt < 4; ++kt)
#pragma unroll
    for (int half = 0; half < 2; ++half)
#pragma unroll
      for (int r = 0; r < 4; ++r) {
        int eidx = (b * 512 + q0 + quad * 4 + r) * 512 + key_base + kt * 32 + half * 16 + l16;
        float ev = a.eg[eidx];
        int sg = a.segp[eidx];
        S[kt][half][r] = S[kt][half][r] * 0.125f + sAh[sg] * ev + sCh[sg];
      }
  // ---- two-pass softmax on the wave's slice (rows live in 16-lane quads) ----
  float m_w[4], l_w[4];
#pragma unroll
  for (int r = 0; r < 4; ++r) {
    float mx = -3.4e38f;
#pragma unroll
    for (int kt = 0; kt < 4; ++kt) { mx = fmaxf(mx, fmaxf(S[kt][0][r], S[kt][1][r])); }
    for (int off = 1; off < 16; off <<= 1) mx = fmaxf(mx, __shfl_xor(mx, off, 64));
    float s = 0.f;
#pragma unroll
    for (int kt = 0; kt < 4; ++kt)
#pragma unroll
      for (int half = 0; half < 2; ++half) {
        float p = exp2f((S[kt][half][r] - mx) * LOG2E);
        S[kt][half][r] = p; s += p;
      }
    for (int off = 1; off < 16; off <<= 1) s += __shfl_xor(s, off, 64);
    m_w[r] = mx; l_w[r] = s;
  }
  // ---- PV over the slice: P C-layout -> A-layout via wave-private LDS ----
  f32x4 Oacc[4] = {{0.f,0.f,0.f,0.f},{0.f,0.f,0.f,0.f},{0.f,0.f,0.f,0.f},{0.f,0.f,0.f,0.f}};
#pragma unroll
  for (int kt = 0; kt < 4; ++kt) {
    int key0 = key_base + kt * 32;
#pragma unroll
    for (int half = 0; half < 2; ++half)
#pragma unroll
      for (int r = 0; r < 4; ++r)
        sP[wave][quad * 4 + r][half * 16 + l16] = f2bf(S[kt][half][r]);
    __builtin_amdgcn_wave_barrier();  // per-wave DS ops are in-order; fence compiler only
    bf16x8 pf = *(const bf16x8*)&sP[wave][l16][quad * 8];
    __builtin_amdgcn_wave_barrier();
#pragma unroll
    for (int nt = 0; nt < 4; ++nt) {
      bf16x8 vf = *(const bf16x8*)(Vt + ((size_t)bh * 64 + nt * 16 + l16) * 512 + key0 + quad * 8);
      Oacc[nt] = __builtin_amdgcn_mfma_f32_16x16x32_bf16(pf, vf, Oacc[nt], 0, 0, 0);
    }
  }
  // ---- combine the 4 wave-partials (flash rescale) ----
  if (l16 == 0) {
#pragma unroll
    for (int r = 0; r < 4; ++r) { sM[wave][quad * 4 + r] = m_w[r]; sL[wave][quad * 4 + r] = l_w[r]; }
  }
#pragma unroll
  for (int nt = 0; nt < 4; ++nt)
#pragma unroll
    for (int r = 0; r < 4; ++r)
      sO[wave][nt][quad * 4 + r][l16] = Oacc[nt][r];
  __syncthreads();
  // wave w finalizes d-chunk nt=w for all 16 rows
#pragma unroll
  for (int r = 0; r < 4; ++r) {
    int row = quad * 4 + r;
    float M = fmaxf(fmaxf(sM[0][row], sM[1][row]), fmaxf(sM[2][row], sM[3][row]));
    float L = 0.f, Ov = 0.f;
#pragma unroll
    for (int wv = 0; wv < 4; ++wv) {
      float f = exp2f((sM[wv][row] - M) * LOG2E);
      L += f * sL[wv][row];
      Ov += f * sO[wv][wave][row][l16];
    }
    float v = Ov / L;
    (a.wsb + AO_OFF)[((size_t)(b * 512 + q0 + row)) * 512 + h * 64 + wave * 16 + l16] = f2bf(v);
  }
}

// ---------------- launch 1: prep (block 0) + weight transpose + x convert (flat) ------
__global__ __launch_bounds__(256) void k_pre(MegaArgs a) {
  __shared__ __align__(16) char smem[36928];
  int blk = blockIdx.x;
  if (blk == 0) prep_block(a, smem);
  else if (blk <= 128) transpose2(a, blk - 1, smem);
  else {
    int i = (blk - 129) * 256 + threadIdx.x;  // 1536 units of 256 float4
    int region = i >> 17, off = i & 131071;
    const float* src = (region == 0) ? a.xq : (region == 1) ? a.xk : a.xv;
    float4 v = ((const float4*)src)[off];
    ushort4 o;
    o.x = f2bf(v.x); o.y = f2bf(v.y); o.z = f2bf(v.z); o.w = f2bf(v.w);
    ((ushort4*)a.wsb)[i] = o;
  }
}

// ---------------- launch 2: QKV GEMM (384 blocks) + edge seg index (512 blocks) -------
__global__ __launch_bounds__(256) void k_qkv(MegaArgs a) {
  __shared__ __align__(16) char smem[18432];
  int blk = blockIdx.x;
  if (blk < 384) {
    int z = blk >> 7, rem = blk & 127;
    const unsigned short* A  = a.wsb + ((z == 0) ? XQ_OFF : (z == 1) ? XK_OFF : XV_OFF);
    const unsigned short* Wt = a.wsb + ((z == 0) ? WQ_OFF : (z == 1) ? WK_OFF : WV_OFF);
    const float* bias = (z == 0) ? a.bq : (z == 1) ? a.bk : a.bv;
    void* outp = (void*)(a.wsb + ((z == 0) ? QB_OFF : (z == 1) ? KB_OFF : VT_OFF));
    gemm_tile(A, Wt, bias, outp, (z == 2) ? 2 : 0, (rem & 15) * 64, (rem >> 4) * 64, smem);
  } else {
    seg_block(a, blk - 384, smem);
  }
}

// ---------------- launch 3: attention ----------------
__global__ __launch_bounds__(256) void k_at(MegaArgs a) {
  __shared__ __align__(16) char smem[26128];
  int blk = blockIdx.x;
  attn_block(a, blk & 31, (blk >> 5) & 7, blk >> 8, smem);
}

// ---------------- launch 4: output GEMM ----------------
__global__ __launch_bounds__(256) void k_og(MegaArgs a) {
  __shared__ __align__(16) char smem[18432];
  gemm_tile(a.wsb + AO_OFF, a.wsb + WO_OFF, a.bo, (void*)a.out, 1,
            (blockIdx.x & 15) * 64, (blockIdx.x >> 4) * 64, smem);
}

extern "C" void kernel_launch(void* const* d_in, const int* in_sizes, int n_in,
                              void* d_out, int out_size, void* d_ws, size_t ws_size,
                              hipStream_t stream) {
  MegaArgs a;
  a.xq  = (const float*)d_in[0];
  a.xk  = (const float*)d_in[1];
  a.xv  = (const float*)d_in[2];
  a.eg  = (const float*)d_in[3];
  a.wq  = (const float*)d_in[4];
  a.bq  = (const float*)d_in[5];
  a.wk  = (const float*)d_in[6];
  a.bk  = (const float*)d_in[7];
  a.wv  = (const float*)d_in[8];
  a.bv  = (const float*)d_in[9];
  a.wo  = (const float*)d_in[10];
  a.bo  = (const float*)d_in[11];
  a.w1  = (const float*)d_in[12];
  a.b1  = (const float*)d_in[13];
  a.we2 = (const float*)d_in[14];
  a.be2 = (const float*)d_in[15];
  a.out = (float*)d_out;
  a.wsb = (unsigned short*)d_ws;
  a.wsT = (float*)((char*)d_ws + T_B);
  a.wsA = (float*)((char*)d_ws + A_B);
  a.wsC = (float*)((char*)d_ws + C_B);
  a.segp = (unsigned short*)((char*)d_ws + SEG_B);

  k_pre<<<1665, 256, 0, stream>>>(a);
  k_qkv<<<896, 256, 0, stream>>>(a);
  k_at<<<512, 256, 0, stream>>>(a);
  k_og<<<128, 256, 0, stream>>>(a);
}